// Round 1
// baseline (3278.646 us; speedup 1.0000x reference)
//
#include <hip/hip_runtime.h>
#include <hip/hip_bf16.h>
#include <math.h>

#define S 4096
#define H 32
#define D 128
#define RR 64
#define QLR 1536
#define HID 2048
#define TOPK_N 2048
#define NEGF (-1e30f)

// ---------------------------------------------------------------------------
// Generic f32 tiled GEMM: C = alpha * A(MxK) @ B(KxN), all row-major.
// ---------------------------------------------------------------------------
template<int BM, int BN, int BK, int TM, int TN>
__global__ __launch_bounds__(256) void gemm_f32(
    const float* __restrict__ A, const float* __restrict__ B, float* __restrict__ C,
    int M, int N, int K, float alpha)
{
    constexpr int TX = BN / TN;
    constexpr int TY = BM / TM;
    static_assert(TX * TY == 256, "bad tile config");
    __shared__ float As[BK][BM + 4];
    __shared__ float Bs[BK][BN + 4];
    const int tid = threadIdx.x;
    const int row0 = blockIdx.y * BM;
    const int col0 = blockIdx.x * BN;
    const int tx = tid % TX;
    const int ty = tid / TX;

    constexpr int A_TPR = BK / 4;              // threads per A row (float4 each)
    constexpr int A_ROWS_PASS = 256 / A_TPR;
    constexpr int A_PASSES = BM / A_ROWS_PASS;
    const int a_m = tid / A_TPR;
    const int a_k4 = (tid % A_TPR) * 4;

    constexpr int B_TPR = BN / 4;
    constexpr int B_ROWS_PASS = 256 / B_TPR;
    constexpr int B_PASSES = (BK + B_ROWS_PASS - 1) / B_ROWS_PASS;
    const int b_n4 = (tid % B_TPR) * 4;
    const int b_k = tid / B_TPR;

    float acc[TM][TN] = {};

    for (int kc = 0; kc < K; kc += BK) {
#pragma unroll
        for (int u = 0; u < A_PASSES; ++u) {
            int m = a_m + u * A_ROWS_PASS;
            float4 x = *(const float4*)&A[(size_t)(row0 + m) * K + kc + a_k4];
            As[a_k4 + 0][m] = x.x; As[a_k4 + 1][m] = x.y;
            As[a_k4 + 2][m] = x.z; As[a_k4 + 3][m] = x.w;
        }
#pragma unroll
        for (int u = 0; u < B_PASSES; ++u) {
            int kk = b_k + u * B_ROWS_PASS;
            if (kk < BK)
                *(float4*)&Bs[kk][b_n4] = *(const float4*)&B[(size_t)(kc + kk) * N + col0 + b_n4];
        }
        __syncthreads();
#pragma unroll
        for (int kk = 0; kk < BK; ++kk) {
            float a[TM], b[TN];
#pragma unroll
            for (int i = 0; i < TM; ++i) a[i] = As[kk][ty * TM + i];
#pragma unroll
            for (int j = 0; j < TN; ++j) b[j] = Bs[kk][tx * TN + j];
#pragma unroll
            for (int i = 0; i < TM; ++i)
#pragma unroll
                for (int j = 0; j < TN; ++j)
                    acc[i][j] = fmaf(a[i], b[j], acc[i][j]);
        }
        __syncthreads();
    }
#pragma unroll
    for (int i = 0; i < TM; ++i) {
        int r = row0 + ty * TM + i;
#pragma unroll
        for (int j = 0; j < TN; ++j)
            C[(size_t)r * N + col0 + tx * TN + j] = alpha * acc[i][j];
    }
}

// ---------------------------------------------------------------------------
// RoPE cos/sin table (double precision to match np float64 trig semantics)
// ---------------------------------------------------------------------------
__global__ void sincos_table_kernel(const int* __restrict__ positions,
                                    float* __restrict__ cosT, float* __restrict__ sinT)
{
    int g = blockIdx.x * blockDim.x + threadIdx.x;  // S*32 total
    if (g >= S * 32) return;
    int s = g >> 5;
    int p = g & 31;
    double inv = pow(10000.0, -((double)(2 * p)) / 64.0);
    double ang = (double)positions[s] * inv;
    cosT[g] = (float)cos(ang);
    sinT[g] = (float)sin(ang);
}

// ---------------------------------------------------------------------------
// Per-row postprocess: optional LayerNorm, RoPE (first 64, interleaved), FWHT
// One block (128 threads) per row of 128 floats. For q: heads=32, for k: heads=1
// ---------------------------------------------------------------------------
__global__ __launch_bounds__(128) void post_kernel(
    float* __restrict__ x, const float* __restrict__ cosT, const float* __restrict__ sinT,
    const float* __restrict__ gamma, const float* __restrict__ beta,
    int heads, int do_ln)
{
    const int row = blockIdx.x;
    const int t = threadIdx.x;
    const int srow = row / heads;
    __shared__ float sm[128];
    __shared__ float red[2];

    float v = x[(size_t)row * 128 + t];

    if (do_ln) {
        float sv = v;
#pragma unroll
        for (int o = 32; o > 0; o >>= 1) sv += __shfl_down(sv, o);
        if ((t & 63) == 0) red[t >> 6] = sv;
        __syncthreads();
        float mu = (red[0] + red[1]) * (1.0f / 128.0f);
        __syncthreads();
        float d = v - mu;
        float sq = d * d;
#pragma unroll
        for (int o = 32; o > 0; o >>= 1) sq += __shfl_down(sq, o);
        if ((t & 63) == 0) red[t >> 6] = sq;
        __syncthreads();
        float var = (red[0] + red[1]) * (1.0f / 128.0f);
        v = d * rsqrtf(var + 1e-6f) * gamma[t] + beta[t];
        __syncthreads();
    }
    sm[t] = v;
    __syncthreads();

    // RoPE on first 64 elements (32 interleaved pairs)
    if (t < 32) {
        float c = cosT[(size_t)srow * 32 + t];
        float sn = sinT[(size_t)srow * 32 + t];
        float xe = sm[2 * t];
        float xo = sm[2 * t + 1];
        sm[2 * t]     = xe * c - xo * sn;
        sm[2 * t + 1] = xe * sn + xo * c;
    }
    __syncthreads();

    // FWHT over 128 (7 stages), same butterfly order as reference
    for (int hstep = 1; hstep < 128; hstep <<= 1) {
        int i = 0; float a = 0.f, b = 0.f;
        bool act = (t < 64);
        if (act) {
            i = ((t & ~(hstep - 1)) << 1) | (t & (hstep - 1));
            a = sm[i];
            b = sm[i + hstep];
        }
        __syncthreads();
        if (act) { sm[i] = a + b; sm[i + hstep] = a - b; }
        __syncthreads();
    }
    x[(size_t)row * 128 + t] = sm[t] * 0.08838834764831845f;  // 128^-0.5
}

// ---------------------------------------------------------------------------
// logits[i,j] = sum_h w[i,h] * relu(q[i,h,:] . k[j,:]),  masked j>i -> NEG
// 128x128 tile per block, 256 threads, 8x8 micro-tile, per-head relu+weight.
// ---------------------------------------------------------------------------
__global__ __launch_bounds__(256) void logits_kernel(
    const float* __restrict__ q,   // S x (H*D)
    const float* __restrict__ k,   // S x D
    const float* __restrict__ w,   // S x H
    float* __restrict__ out)       // S x S
{
    const int bx = blockIdx.x, by = blockIdx.y;
    const int row0 = by * 128, col0 = bx * 128;
    const int tid = threadIdx.x;

    if (bx > by) {
        // entire tile strictly above diagonal: fill NEG
        const float4 n4 = make_float4(NEGF, NEGF, NEGF, NEGF);
        int c = (tid & 31) * 4;
        for (int r = tid >> 5; r < 128; r += 8)
            *(float4*)&out[(size_t)(row0 + r) * S + col0 + c] = n4;
        return;
    }

    __shared__ float As[32][132];
    __shared__ float Bs[32][132];
    __shared__ float Ws[128][32];

    // stage w tile (128 rows x 32 heads, contiguous copy)
    {
        const float4* wsrc = (const float4*)(w + (size_t)row0 * 32);
        float4* wdst = (float4*)&Ws[0][0];
#pragma unroll
        for (int u = 0; u < 4; ++u) wdst[tid + u * 256] = wsrc[tid + u * 256];
    }

    const int tx = tid & 15, ty = tid >> 4;
    const int a_m = tid >> 3;         // 0..31
    const int a_k4 = (tid & 7) * 4;   // 0,4,...,28

    float accP[8][8] = {};

    for (int h = 0; h < H; ++h) {
        float accH[8][8] = {};
#pragma unroll
        for (int kc = 0; kc < 128; kc += 32) {
            // stage A: q rows, head h slice, transposed into As[k][m]
#pragma unroll
            for (int u = 0; u < 4; ++u) {
                int m = a_m + u * 32;
                float4 x4 = *(const float4*)&q[(size_t)(row0 + m) * (H * D) + h * D + kc + a_k4];
                As[a_k4 + 0][m] = x4.x; As[a_k4 + 1][m] = x4.y;
                As[a_k4 + 2][m] = x4.z; As[a_k4 + 3][m] = x4.w;
            }
            // stage B: k rows transposed into Bs[k][n]
#pragma unroll
            for (int u = 0; u < 4; ++u) {
                int m = a_m + u * 32;
                float4 x4 = *(const float4*)&k[(size_t)(col0 + m) * D + kc + a_k4];
                Bs[a_k4 + 0][m] = x4.x; Bs[a_k4 + 1][m] = x4.y;
                Bs[a_k4 + 2][m] = x4.z; Bs[a_k4 + 3][m] = x4.w;
            }
            __syncthreads();
#pragma unroll
            for (int kk = 0; kk < 32; ++kk) {
                float4 a0 = *(const float4*)&As[kk][ty * 4];
                float4 a1 = *(const float4*)&As[kk][64 + ty * 4];
                float4 b0 = *(const float4*)&Bs[kk][tx * 4];
                float4 b1 = *(const float4*)&Bs[kk][64 + tx * 4];
                float av[8] = {a0.x, a0.y, a0.z, a0.w, a1.x, a1.y, a1.z, a1.w};
                float bv[8] = {b0.x, b0.y, b0.z, b0.w, b1.x, b1.y, b1.z, b1.w};
#pragma unroll
                for (int i = 0; i < 8; ++i)
#pragma unroll
                    for (int j = 0; j < 8; ++j)
                        accH[i][j] = fmaf(av[i], bv[j], accH[i][j]);
            }
            __syncthreads();
        }
        // relu + weight + accumulate
#pragma unroll
        for (int i = 0; i < 8; ++i) {
            int rl = (i < 4) ? (ty * 4 + i) : (64 + ty * 4 + (i - 4));
            float wv = Ws[rl][h];
#pragma unroll
            for (int j = 0; j < 8; ++j)
                accP[i][j] = fmaf(wv, fmaxf(accH[i][j], 0.0f), accP[i][j]);
        }
    }

    // write with causal mask
#pragma unroll
    for (int i = 0; i < 8; ++i) {
        int r = row0 + ((i < 4) ? (ty * 4 + i) : (64 + ty * 4 + (i - 4)));
#pragma unroll
        for (int j = 0; j < 8; ++j) {
            int c = col0 + ((j < 4) ? (tx * 4 + j) : (64 + tx * 4 + (j - 4)));
            out[(size_t)r * S + c] = (c <= r) ? accP[i][j] : NEGF;
        }
    }
}

// ---------------------------------------------------------------------------
// Top-k per row: full bitonic sort of 4096 packed 64-bit keys in LDS.
// Key = (monotonic(float) << 32) | (0xFFFFFFFF - idx): descending sort gives
// values descending, ties -> smaller index first (jax.lax.top_k semantics).
// Writes indices as FLOAT values; -1.0f where val <= NEG*0.5.
// ---------------------------------------------------------------------------
__device__ __forceinline__ unsigned mono32(float f)
{
    unsigned u = __float_as_uint(f);
    return (u & 0x80000000u) ? ~u : (u | 0x80000000u);
}

__global__ __launch_bounds__(256) void topk_kernel(
    const float* __restrict__ logits, float* __restrict__ out_idx)
{
    const int row = blockIdx.x;
    __shared__ unsigned long long sm[S];
    const float* lr = logits + (size_t)row * S;

    for (int j = threadIdx.x; j < S; j += 256) {
        unsigned long long key = ((unsigned long long)mono32(lr[j]) << 32)
                               | (unsigned)(0xFFFFFFFFu - (unsigned)j);
        sm[j] = key;
    }
    __syncthreads();

    for (unsigned k = 2; k <= (unsigned)S; k <<= 1) {
        for (unsigned j = k >> 1; j > 0; j >>= 1) {
            for (unsigned t = threadIdx.x; t < S / 2; t += 256) {
                unsigned i = 2 * t - (t & (j - 1));
                unsigned p = i | j;
                bool up = (i & k) != 0;
                unsigned long long a = sm[i], b = sm[p];
                if ((a < b) != up) { sm[i] = b; sm[p] = a; }
            }
            __syncthreads();
        }
    }

    const unsigned cut = mono32(-5e29f);  // vals > NEG*0.5
    for (int p = threadIdx.x; p < TOPK_N; p += 256) {
        unsigned long long e = sm[p];
        unsigned m = (unsigned)(e >> 32);
        int idx = (int)(0xFFFFFFFFu - (unsigned)(e & 0xFFFFFFFFu));
        out_idx[(size_t)row * TOPK_N + p] = (m > cut) ? (float)idx : -1.0f;
    }
}

// ---------------------------------------------------------------------------
extern "C" void kernel_launch(void* const* d_in, const int* in_sizes, int n_in,
                              void* d_out, int out_size, void* d_ws, size_t ws_size,
                              hipStream_t stream)
{
    const float* hidden  = (const float*)d_in[0];   // S x HID
    const float* q_lora  = (const float*)d_in[1];   // S x QLR
    const int*   positions = (const int*)d_in[2];   // S
    const float* Wq      = (const float*)d_in[3];   // QLR x H*D
    const float* Wk      = (const float*)d_in[4];   // HID x D
    const float* k_gamma = (const float*)d_in[5];   // D
    const float* k_beta  = (const float*)d_in[6];   // D
    const float* Wp      = (const float*)d_in[7];   // HID x H

    char* ws = (char*)d_ws;
    float* q    = (float*)(ws);                                   // S*H*D f32 = 64 MB
    float* kbuf = (float*)(ws + (size_t)S * H * D * 4);           // S*D = 2 MB
    float* wbuf = (float*)(ws + (size_t)S * H * D * 4 + (size_t)S * D * 4);        // S*H
    float* cosT = (float*)(ws + (size_t)S * H * D * 4 + (size_t)S * D * 4 + (size_t)S * H * 4);
    float* sinT = cosT + (size_t)S * 32;

    float* out_logits = (float*)d_out;
    float* out_idx = out_logits + (size_t)S * S;

    // 1) q = q_lora @ Wq             (4096 x 4096 x 1536)
    gemm_f32<128, 128, 32, 8, 8><<<dim3((H * D) / 128, S / 128), 256, 0, stream>>>(
        q_lora, Wq, q, S, H * D, QLR, 1.0f);

    // 2) k = hidden @ Wk             (4096 x 128 x 2048)
    gemm_f32<64, 64, 32, 4, 4><<<dim3(D / 64, S / 64), 256, 0, stream>>>(
        hidden, Wk, kbuf, S, D, HID, 1.0f);

    // 3) w = hidden @ Wp * (H*D)^-0.5   (4096 x 32 x 2048), alpha = 1/64
    gemm_f32<64, 32, 32, 4, 2><<<dim3(1, S / 64), 256, 0, stream>>>(
        hidden, Wp, wbuf, S, H, HID, 0.015625f);

    // 4) RoPE trig table (double precision)
    sincos_table_kernel<<<(S * 32) / 256, 256, 0, stream>>>(positions, cosT, sinT);

    // 5) k: LN + RoPE + FWHT (in place)
    post_kernel<<<S, 128, 0, stream>>>(kbuf, cosT, sinT, k_gamma, k_beta, 1, 1);

    // 6) q: RoPE + FWHT (in place), one row per (s,h)
    post_kernel<<<S * H, 128, 0, stream>>>(q, cosT, sinT, nullptr, nullptr, H, 0);

    // 7) logits with causal mask
    logits_kernel<<<dim3(S / 128, S / 128), 256, 0, stream>>>(q, kbuf, wbuf, out_logits);

    // 8) top-k indices (written as float values)
    topk_kernel<<<S, 256, 0, stream>>>(out_logits, out_idx);
}

// Round 3
// 716.464 us; speedup vs baseline: 4.5761x; 4.5761x over previous
//
#include <hip/hip_runtime.h>
#include <hip/hip_bf16.h>
#include <math.h>

#define S 4096
#define H 32
#define D 128
#define QLR 1536
#define HID 2048
#define TOPK_N 2048
#define NEGF (-1e30f)

typedef __attribute__((ext_vector_type(8))) short bf16x8;
typedef __attribute__((ext_vector_type(4))) float f32x4;

__device__ __forceinline__ void async_copy16(const void* g, void* l) {
    __builtin_amdgcn_global_load_lds(
        (const __attribute__((address_space(1))) unsigned int*)g,
        (__attribute__((address_space(3))) unsigned int*)l,
        16, 0, 0);
}

__device__ __forceinline__ unsigned short bf16bits(float f) {
    __hip_bfloat16 h = __float2bfloat16(f);
    return *(unsigned short*)&h;
}

// ---------------------------------------------------------------------------
// Generic f32 tiled GEMM (kept for the two small GEMMs: k and w)
// ---------------------------------------------------------------------------
template<int BM, int BN, int BK, int TM, int TN>
__global__ __launch_bounds__(256) void gemm_f32(
    const float* __restrict__ A, const float* __restrict__ B, float* __restrict__ C,
    int M, int N, int K, float alpha)
{
    constexpr int TX = BN / TN;
    constexpr int TY = BM / TM;
    static_assert(TX * TY == 256, "bad tile config");
    __shared__ float As[BK][BM + 4];
    __shared__ float Bs[BK][BN + 4];
    const int tid = threadIdx.x;
    const int row0 = blockIdx.y * BM;
    const int col0 = blockIdx.x * BN;
    const int tx = tid % TX;
    const int ty = tid / TX;

    constexpr int A_TPR = BK / 4;
    constexpr int A_ROWS_PASS = 256 / A_TPR;
    constexpr int A_PASSES = BM / A_ROWS_PASS;
    const int a_m = tid / A_TPR;
    const int a_k4 = (tid % A_TPR) * 4;

    constexpr int B_TPR = BN / 4;
    constexpr int B_ROWS_PASS = 256 / B_TPR;
    constexpr int B_PASSES = (BK + B_ROWS_PASS - 1) / B_ROWS_PASS;
    const int b_n4 = (tid % B_TPR) * 4;
    const int b_k = tid / B_TPR;

    float acc[TM][TN] = {};

    for (int kc = 0; kc < K; kc += BK) {
#pragma unroll
        for (int u = 0; u < A_PASSES; ++u) {
            int m = a_m + u * A_ROWS_PASS;
            float4 x = *(const float4*)&A[(size_t)(row0 + m) * K + kc + a_k4];
            As[a_k4 + 0][m] = x.x; As[a_k4 + 1][m] = x.y;
            As[a_k4 + 2][m] = x.z; As[a_k4 + 3][m] = x.w;
        }
#pragma unroll
        for (int u = 0; u < B_PASSES; ++u) {
            int kk = b_k + u * B_ROWS_PASS;
            if (kk < BK)
                *(float4*)&Bs[kk][b_n4] = *(const float4*)&B[(size_t)(kc + kk) * N + col0 + b_n4];
        }
        __syncthreads();
#pragma unroll
        for (int kk = 0; kk < BK; ++kk) {
            float a[TM], b[TN];
#pragma unroll
            for (int i = 0; i < TM; ++i) a[i] = As[kk][ty * TM + i];
#pragma unroll
            for (int j = 0; j < TN; ++j) b[j] = Bs[kk][tx * TN + j];
#pragma unroll
            for (int i = 0; i < TM; ++i)
#pragma unroll
                for (int j = 0; j < TN; ++j)
                    acc[i][j] = fmaf(a[i], b[j], acc[i][j]);
        }
        __syncthreads();
    }
#pragma unroll
    for (int i = 0; i < TM; ++i) {
        int r = row0 + ty * TM + i;
#pragma unroll
        for (int j = 0; j < TN; ++j)
            C[(size_t)r * N + col0 + tx * TN + j] = alpha * acc[i][j];
    }
}

// ---------------------------------------------------------------------------
// Cast f32 -> bf16 (elementwise, float4 granular)
// ---------------------------------------------------------------------------
__global__ __launch_bounds__(256) void cast_bf16_kernel(
    const float* __restrict__ in, __hip_bfloat16* __restrict__ out, int n4)
{
    int i = blockIdx.x * blockDim.x + threadIdx.x;
    if (i < n4) {
        float4 v = ((const float4*)in)[i];
        ushort4 pack;
        pack.x = bf16bits(v.x);
        pack.y = bf16bits(v.y);
        pack.z = bf16bits(v.z);
        pack.w = bf16bits(v.w);
        *(ushort4*)(out + (size_t)i * 4) = pack;
    }
}

// ---------------------------------------------------------------------------
// Transpose + cast: Wq (1536 x 4096 f32) -> WqT (4096 x 1536 bf16)
// ---------------------------------------------------------------------------
__global__ __launch_bounds__(256) void transpose_cast_kernel(
    const float* __restrict__ in, __hip_bfloat16* __restrict__ out)
{
    __shared__ float sm[32][33];
    const int nb = blockIdx.x;   // 0..127 over N=4096
    const int kb = blockIdx.y;   // 0..47  over K=1536
    const int t = threadIdx.x;
    const int j = t & 31, i0 = t >> 5;
#pragma unroll
    for (int u = 0; u < 4; ++u) {
        int i = i0 + u * 8;
        sm[i][j] = in[(size_t)(kb * 32 + i) * 4096 + nb * 32 + j];
    }
    __syncthreads();
#pragma unroll
    for (int u = 0; u < 4; ++u) {
        int i = i0 + u * 8;
        out[(size_t)(nb * 32 + i) * 1536 + kb * 32 + j] = __float2bfloat16(sm[j][i]);
    }
}

// ---------------------------------------------------------------------------
// bf16 MFMA GEMM, B^T layout: C(MxN,bf16) = A(MxK,bf16) @ BT(NxK,bf16)^T
// 128x128 tile, BK=32, global_load_lds staging (m97 structure).
// ---------------------------------------------------------------------------
__global__ __launch_bounds__(256, 2) void gemm_bf16_bt(
    const __hip_bfloat16* __restrict__ A, const __hip_bfloat16* __restrict__ BT,
    __hip_bfloat16* __restrict__ C, int M, int N, int K)
{
    __shared__ short As[128 * 32];
    __shared__ short Bs[128 * 32];
    const int tid = threadIdx.x;
    const int wave = tid >> 6, lane = tid & 63, grp = lane >> 4, lm = lane & 15;
    const int row0 = blockIdx.y * 128, col0 = blockIdx.x * 128;
    const short* Ag = (const short*)A;
    const short* Bg = (const short*)BT;

    f32x4 acc[2][8] = {};

    for (int kc = 0; kc < K; kc += 32) {
        __syncthreads();
#pragma unroll
        for (int is = 0; is < 2; ++is) {
            int r = is * 64 + (tid >> 2);
            async_copy16(Ag + (size_t)(row0 + r) * K + kc + (tid & 3) * 8,
                         (void*)(As + is * 2048 + wave * 512));
            async_copy16(Bg + (size_t)(col0 + r) * K + kc + (tid & 3) * 8,
                         (void*)(Bs + is * 2048 + wave * 512));
        }
        __syncthreads();
        bf16x8 a0 = *(const bf16x8*)(As + (wave * 32 + lm) * 32 + grp * 8);
        bf16x8 a1 = *(const bf16x8*)(As + (wave * 32 + 16 + lm) * 32 + grp * 8);
#pragma unroll
        for (int c = 0; c < 8; ++c) {
            bf16x8 b = *(const bf16x8*)(Bs + (c * 16 + lm) * 32 + grp * 8);
            acc[0][c] = __builtin_amdgcn_mfma_f32_16x16x32_bf16(a0, b, acc[0][c], 0, 0, 0);
            acc[1][c] = __builtin_amdgcn_mfma_f32_16x16x32_bf16(a1, b, acc[1][c], 0, 0, 0);
        }
    }
#pragma unroll
    for (int t = 0; t < 2; ++t)
#pragma unroll
        for (int c = 0; c < 8; ++c)
#pragma unroll
            for (int r = 0; r < 4; ++r) {
                int rr = row0 + wave * 32 + t * 16 + grp * 4 + r;
                int cc = col0 + c * 16 + lm;
                C[(size_t)rr * N + cc] = __float2bfloat16(acc[t][c][r]);
            }
}

// ---------------------------------------------------------------------------
// RoPE cos/sin table
// ---------------------------------------------------------------------------
__global__ void sincos_table_kernel(const int* __restrict__ positions,
                                    float* __restrict__ cosT, float* __restrict__ sinT)
{
    int g = blockIdx.x * blockDim.x + threadIdx.x;
    if (g >= S * 32) return;
    int s = g >> 5;
    int p = g & 31;
    double inv = pow(10000.0, -((double)(2 * p)) / 64.0);
    double ang = (double)positions[s] * inv;
    cosT[g] = (float)cos(ang);
    sinT[g] = (float)sin(ang);
}

// ---------------------------------------------------------------------------
// Per-row postprocess: optional LN, RoPE, FWHT. Reads f32 or bf16, writes bf16.
// ---------------------------------------------------------------------------
__global__ __launch_bounds__(128) void post_kernel(
    const void* in, int in_bf16, __hip_bfloat16* outb,
    const float* __restrict__ cosT, const float* __restrict__ sinT,
    const float* __restrict__ gamma, const float* __restrict__ beta,
    int heads, int do_ln)
{
    const int row = blockIdx.x;
    const int t = threadIdx.x;
    const int srow = row / heads;
    __shared__ float sm[128];
    __shared__ float red[2];

    float v;
    if (in_bf16) v = __bfloat162float(((const __hip_bfloat16*)in)[(size_t)row * 128 + t]);
    else         v = ((const float*)in)[(size_t)row * 128 + t];

    if (do_ln) {
        float sv = v;
#pragma unroll
        for (int o = 32; o > 0; o >>= 1) sv += __shfl_down(sv, o);
        if ((t & 63) == 0) red[t >> 6] = sv;
        __syncthreads();
        float mu = (red[0] + red[1]) * (1.0f / 128.0f);
        __syncthreads();
        float d = v - mu;
        float sq = d * d;
#pragma unroll
        for (int o = 32; o > 0; o >>= 1) sq += __shfl_down(sq, o);
        if ((t & 63) == 0) red[t >> 6] = sq;
        __syncthreads();
        float var = (red[0] + red[1]) * (1.0f / 128.0f);
        v = d * rsqrtf(var + 1e-6f) * gamma[t] + beta[t];
        __syncthreads();
    }
    sm[t] = v;
    __syncthreads();

    if (t < 32) {
        float c = cosT[(size_t)srow * 32 + t];
        float sn = sinT[(size_t)srow * 32 + t];
        float xe = sm[2 * t];
        float xo = sm[2 * t + 1];
        sm[2 * t]     = xe * c - xo * sn;
        sm[2 * t + 1] = xe * sn + xo * c;
    }
    __syncthreads();

    for (int hstep = 1; hstep < 128; hstep <<= 1) {
        int i = 0; float a = 0.f, b = 0.f;
        bool act = (t < 64);
        if (act) {
            i = ((t & ~(hstep - 1)) << 1) | (t & (hstep - 1));
            a = sm[i];
            b = sm[i + hstep];
        }
        __syncthreads();
        if (act) { sm[i] = a + b; sm[i + hstep] = a - b; }
        __syncthreads();
    }
    outb[(size_t)row * 128 + t] = __float2bfloat16(sm[t] * 0.08838834764831845f);
}

// ---------------------------------------------------------------------------
// MFMA logits: logits[i,j] = sum_h w[i,h]*relu(q[i,h,:].k[j,:]), causal mask.
// 128x128 tile, Bs(k tile) resident for all heads, As(q slice) staged per head.
// 16B-chunk XOR swizzle on both tiles -> 2-way (free) LDS access.
// ---------------------------------------------------------------------------
__global__ __launch_bounds__(256, 2) void logits_mfma(
    const short* __restrict__ qb,   // S x (H*D) bf16 bits
    const short* __restrict__ kb,   // S x D bf16 bits
    const float* __restrict__ w,    // S x H
    float* __restrict__ out)
{
    const int bx = blockIdx.x, by = blockIdx.y;
    const int row0 = by * 128, col0 = bx * 128;
    const int tid = threadIdx.x;

    if (bx > by) {
        const float4 n4 = make_float4(NEGF, NEGF, NEGF, NEGF);
        int c = (tid & 31) * 4;
        for (int r = tid >> 5; r < 128; r += 8)
            *(float4*)&out[(size_t)(row0 + r) * S + col0 + c] = n4;
        return;
    }

    __shared__ short As[128 * 128];  // 32 KB
    __shared__ short Bs[128 * 128];  // 32 KB
    const int wave = tid >> 6, lane = tid & 63, grp = lane >> 4, lm = lane & 15;
    const int rhi = tid >> 4;        // 0..15
    const int e = (tid & 15) ^ rhi;  // swizzled 16B chunk index

    // stage k tile once (swizzled source chunks -> linear LDS)
#pragma unroll
    for (int it = 0; it < 8; ++it) {
        int r = it * 16 + rhi;
        async_copy16(kb + (size_t)(col0 + r) * D + e * 8,
                     (void*)(Bs + it * 2048 + wave * 512));
    }

    f32x4 accP[2][8] = {};

    for (int h = 0; h < H; ++h) {
        __syncthreads();  // prev compute done (and first time: Bs staged)
#pragma unroll
        for (int it = 0; it < 8; ++it) {
            int r = it * 16 + rhi;
            async_copy16(qb + (size_t)(row0 + r) * (H * D) + h * D + e * 8,
                         (void*)(As + it * 2048 + wave * 512));
        }
        float wv[2][4];
#pragma unroll
        for (int t = 0; t < 2; ++t)
#pragma unroll
            for (int r = 0; r < 4; ++r)
                wv[t][r] = w[(size_t)(row0 + wave * 32 + t * 16 + grp * 4 + r) * H + h];
        __syncthreads();  // As staged

        f32x4 accH[2][8] = {};
#pragma unroll
        for (int kc = 0; kc < 4; ++kc) {
            int ch = ((kc << 2) + grp) ^ lm;   // swizzled chunk
            bf16x8 a0 = *(const bf16x8*)(As + (wave * 32 + lm) * 128 + ch * 8);
            bf16x8 a1 = *(const bf16x8*)(As + (wave * 32 + 16 + lm) * 128 + ch * 8);
#pragma unroll
            for (int c = 0; c < 8; ++c) {
                bf16x8 b = *(const bf16x8*)(Bs + (c * 16 + lm) * 128 + ch * 8);
                accH[0][c] = __builtin_amdgcn_mfma_f32_16x16x32_bf16(a0, b, accH[0][c], 0, 0, 0);
                accH[1][c] = __builtin_amdgcn_mfma_f32_16x16x32_bf16(a1, b, accH[1][c], 0, 0, 0);
            }
        }
#pragma unroll
        for (int t = 0; t < 2; ++t)
#pragma unroll
            for (int c = 0; c < 8; ++c)
#pragma unroll
                for (int r = 0; r < 4; ++r)
                    accP[t][c][r] += wv[t][r] * fmaxf(accH[t][c][r], 0.0f);
    }

#pragma unroll
    for (int t = 0; t < 2; ++t)
#pragma unroll
        for (int c = 0; c < 8; ++c)
#pragma unroll
            for (int r = 0; r < 4; ++r) {
                int rr = row0 + wave * 32 + t * 16 + grp * 4 + r;
                int cc = col0 + c * 16 + lm;
                out[(size_t)rr * S + cc] = (cc <= rr) ? accP[t][c][r] : NEGF;
            }
}

// ---------------------------------------------------------------------------
// Top-k via 4-round radix select (11-bit digits over unique 44-bit keys).
// key = (mono32(v) << 12) | (4095 - j); select top 2048, emit (unordered).
// Rows with <= 2048 valid columns emit trivially.
// ---------------------------------------------------------------------------
__device__ __forceinline__ unsigned mono32(float f)
{
    unsigned u = __float_as_uint(f);
    return (u & 0x80000000u) ? ~u : (u | 0x80000000u);
}

__global__ __launch_bounds__(256) void topk_select(
    const float* __restrict__ logits, float* __restrict__ out_idx)
{
    const int row = blockIdx.x;
    const int tid = threadIdx.x;
    const int valid = row + 1;
    float* orow = out_idx + (size_t)row * TOPK_N;

    if (valid <= TOPK_N) {
        for (int p = tid; p < TOPK_N; p += 256)
            orow[p] = (p < valid) ? (float)p : -1.0f;
        return;
    }

    __shared__ float vals[S];
    __shared__ unsigned hist[2048];
    __shared__ unsigned chunk[256];
    __shared__ unsigned long long sh_prefix;
    __shared__ int sh_rem;
    __shared__ unsigned sh_cnt;

    const float* lr = logits + (size_t)row * S;
    for (int j = tid; j < valid; j += 256) vals[j] = lr[j];
    if (tid == 0) { sh_prefix = 0ull; sh_rem = TOPK_N; sh_cnt = 0u; }
    __syncthreads();

    for (int rnd = 0; rnd < 4; ++rnd) {
        const int shift = 33 - 11 * rnd;
        for (int i = tid; i < 2048; i += 256) hist[i] = 0u;
        __syncthreads();
        const unsigned long long pref = sh_prefix;
        const int rem = sh_rem;
        const int hs = shift + 11;
        for (int j = tid; j < valid; j += 256) {
            unsigned long long key = (((unsigned long long)mono32(vals[j])) << 12)
                                   | (unsigned)(4095 - j);
            if ((key >> hs) == (pref >> hs))
                atomicAdd(&hist[(unsigned)(key >> shift) & 2047u], 1u);
        }
        __syncthreads();
        unsigned csum = 0;
#pragma unroll
        for (int d = 0; d < 8; ++d) csum += hist[tid * 8 + d];
        chunk[tid] = csum;
        __syncthreads();
        for (int off = 1; off < 256; off <<= 1) {
            unsigned v = (tid + off < 256) ? chunk[tid + off] : 0u;
            __syncthreads();
            chunk[tid] += v;
            __syncthreads();
        }
        unsigned A = (tid < 255) ? chunk[tid + 1] : 0u;
        for (int dd = 7; dd >= 0; --dd) {
            unsigned c = hist[tid * 8 + dd];
            if (c && A < (unsigned)rem && (unsigned)rem <= A + c) {
                sh_prefix = pref | ((unsigned long long)(tid * 8 + dd) << shift);
                sh_rem = rem - (int)A;
            }
            A += c;
        }
        __syncthreads();
    }

    const unsigned long long Kstar = sh_prefix;
    for (int j = tid; j < valid; j += 256) {
        unsigned long long key = (((unsigned long long)mono32(vals[j])) << 12)
                               | (unsigned)(4095 - j);
        if (key >= Kstar) {
            unsigned p = atomicAdd(&sh_cnt, 1u);
            orow[p] = (float)j;
        }
    }
}

// ---------------------------------------------------------------------------
extern "C" void kernel_launch(void* const* d_in, const int* in_sizes, int n_in,
                              void* d_out, int out_size, void* d_ws, size_t ws_size,
                              hipStream_t stream)
{
    const float* hidden    = (const float*)d_in[0];
    const float* q_lora    = (const float*)d_in[1];
    const int*   positions = (const int*)d_in[2];
    const float* Wq        = (const float*)d_in[3];
    const float* Wk        = (const float*)d_in[4];
    const float* k_gamma   = (const float*)d_in[5];
    const float* k_beta    = (const float*)d_in[6];
    const float* Wp        = (const float*)d_in[7];

    char* ws = (char*)d_ws;
    size_t off = 0;
    __hip_bfloat16* qb16 = (__hip_bfloat16*)(ws + off); off += (size_t)S * H * D * 2;   // 32 MB
    __hip_bfloat16* qlb  = (__hip_bfloat16*)(ws + off); off += (size_t)S * QLR * 2;     // 12.6 MB
    __hip_bfloat16* WqT  = (__hip_bfloat16*)(ws + off); off += (size_t)(H * D) * QLR * 2; // 12.6 MB
    float* kf32 = (float*)(ws + off); off += (size_t)S * D * 4;                          // 2 MB
    __hip_bfloat16* kb16 = (__hip_bfloat16*)(ws + off); off += (size_t)S * D * 2;        // 1 MB
    float* wbuf = (float*)(ws + off); off += (size_t)S * H * 4;
    float* cosT = (float*)(ws + off); off += (size_t)S * 32 * 4;
    float* sinT = (float*)(ws + off); off += (size_t)S * 32 * 4;

    float* out_logits = (float*)d_out;
    float* out_idx = out_logits + (size_t)S * S;

    // 1) casts for the q GEMM
    cast_bf16_kernel<<<(S * QLR / 4 + 255) / 256, 256, 0, stream>>>(q_lora, qlb, S * QLR / 4);
    transpose_cast_kernel<<<dim3((H * D) / 32, QLR / 32), 256, 0, stream>>>(Wq, WqT);

    // 2) q = q_lora @ Wq  (bf16 MFMA, bf16 out)
    gemm_bf16_bt<<<dim3((H * D) / 128, S / 128), 256, 0, stream>>>(
        qlb, WqT, qb16, S, H * D, QLR);

    // 3) k = hidden @ Wk (f32), w = hidden @ Wp * (H*D)^-0.5 (f32)
    gemm_f32<64, 64, 32, 4, 4><<<dim3(D / 64, S / 64), 256, 0, stream>>>(
        hidden, Wk, kf32, S, D, HID, 1.0f);
    gemm_f32<64, 32, 32, 4, 2><<<dim3(1, S / 64), 256, 0, stream>>>(
        hidden, Wp, wbuf, S, H, HID, 0.015625f);

    // 4) RoPE trig table
    sincos_table_kernel<<<(S * 32) / 256, 256, 0, stream>>>(positions, cosT, sinT);

    // 5) k: LN + RoPE + FWHT -> bf16 ; q: RoPE + FWHT in place (bf16)
    post_kernel<<<S, 128, 0, stream>>>(kf32, 0, kb16, cosT, sinT, k_gamma, k_beta, 1, 1);
    post_kernel<<<S * H, 128, 0, stream>>>(qb16, 1, qb16, cosT, sinT, nullptr, nullptr, H, 0);

    // 6) logits (bf16 MFMA) with causal mask
    logits_mfma<<<dim3(S / 128, S / 128), 256, 0, stream>>>(
        (const short*)qb16, (const short*)kb16, wbuf, out_logits);

    // 7) top-k indices (radix select, written as float)
    topk_select<<<S, 256, 0, stream>>>(out_logits, out_idx);
}

// Round 4
// 507.093 us; speedup vs baseline: 6.4656x; 1.4129x over previous
//
#include <hip/hip_runtime.h>
#include <hip/hip_bf16.h>
#include <math.h>

#define S 4096
#define H 32
#define D 128
#define QLR 1536
#define HID 2048
#define TOPK_N 2048
#define NEGF (-1e30f)
#define KW_N 160

typedef __attribute__((ext_vector_type(8))) short bf16x8;
typedef __attribute__((ext_vector_type(4))) float f32x4;

__device__ __forceinline__ void async_copy16(const void* g, void* l) {
    __builtin_amdgcn_global_load_lds(
        (const __attribute__((address_space(1))) unsigned int*)g,
        (__attribute__((address_space(3))) unsigned int*)l,
        16, 0, 0);
}

__device__ __forceinline__ unsigned short bf16bits(float f) {
    __hip_bfloat16 h = __float2bfloat16(f);
    return *(unsigned short*)&h;
}

// ---------------------------------------------------------------------------
// Cast f32 -> bf16 (elementwise, float4 granular)
// ---------------------------------------------------------------------------
__global__ __launch_bounds__(256) void cast_bf16_kernel(
    const float* __restrict__ in, __hip_bfloat16* __restrict__ out, int n4)
{
    int i = blockIdx.x * blockDim.x + threadIdx.x;
    if (i < n4) {
        float4 v = ((const float4*)in)[i];
        ushort4 pack;
        pack.x = bf16bits(v.x);
        pack.y = bf16bits(v.y);
        pack.z = bf16bits(v.z);
        pack.w = bf16bits(v.w);
        *(ushort4*)(out + (size_t)i * 4) = pack;
    }
}

__global__ __launch_bounds__(256) void zero_f32(float* __restrict__ p, int n)
{
    int i = blockIdx.x * blockDim.x + threadIdx.x;
    if (i < n) p[i] = 0.0f;
}

// ---------------------------------------------------------------------------
// Transpose + cast: Wq (1536 x 4096 f32) -> WqT (4096 x 1536 bf16)
// ---------------------------------------------------------------------------
__global__ __launch_bounds__(256) void transpose_cast_kernel(
    const float* __restrict__ in, __hip_bfloat16* __restrict__ out)
{
    __shared__ float sm[32][33];
    const int nb = blockIdx.x;
    const int kb = blockIdx.y;
    const int t = threadIdx.x;
    const int j = t & 31, i0 = t >> 5;
#pragma unroll
    for (int u = 0; u < 4; ++u) {
        int i = i0 + u * 8;
        sm[i][j] = in[(size_t)(kb * 32 + i) * 4096 + nb * 32 + j];
    }
    __syncthreads();
#pragma unroll
    for (int u = 0; u < 4; ++u) {
        int i = i0 + u * 8;
        out[(size_t)(nb * 32 + i) * 1536 + kb * 32 + j] = __float2bfloat16(sm[j][i]);
    }
}

// ---------------------------------------------------------------------------
// Build WkpT (160 x 2048 bf16): rows 0..127 = Wk^T, rows 128..159 = (Wp/64)^T
// ---------------------------------------------------------------------------
__global__ __launch_bounds__(256) void build_wkpT(
    const float* __restrict__ Wk, const float* __restrict__ Wp,
    __hip_bfloat16* __restrict__ WkpT)
{
    int g = blockIdx.x * blockDim.x + threadIdx.x;
    if (g >= KW_N * HID) return;
    int n = g / HID, k = g % HID;
    float v = (n < 128) ? Wk[(size_t)k * 128 + n]
                        : Wp[(size_t)k * 32 + (n - 128)] * 0.015625f;
    WkpT[g] = __float2bfloat16(v);
}

// ---------------------------------------------------------------------------
// Fused k/w projection, split-K MFMA: grid (M/64, K/128) = 64 x 16.
// Each block computes 64x160 partial over K-chunk 128, atomicAdds into
// kf32 (cols 0..127) and wbuf (cols 128..159).
// ---------------------------------------------------------------------------
__global__ __launch_bounds__(256, 2) void kw_mfma(
    const short* __restrict__ hb,    // S x HID bf16 bits
    const short* __restrict__ WkpT,  // 160 x HID bf16 bits
    float* __restrict__ kf32,        // S x 128
    float* __restrict__ wbuf)        // S x 32
{
    const int mt = blockIdx.x;   // 0..63
    const int kc = blockIdx.y;   // 0..15
    const int tid = threadIdx.x;
    const int wave = tid >> 6, lane = tid & 63, grp = lane >> 4, lm = lane & 15;
    __shared__ short As[64 * 128];    // 16 KB
    __shared__ short Bs[KW_N * 128];  // 40 KB

    const int rhi = tid >> 4;
    const int e = (tid & 15) ^ rhi;

#pragma unroll
    for (int it = 0; it < 4; ++it) {
        int r = it * 16 + rhi;
        async_copy16(hb + (size_t)(mt * 64 + r) * HID + kc * 128 + e * 8,
                     (void*)(As + it * 2048 + wave * 512));
    }
#pragma unroll
    for (int it = 0; it < 10; ++it) {
        int r = it * 16 + rhi;
        async_copy16(WkpT + (size_t)r * HID + kc * 128 + e * 8,
                     (void*)(Bs + it * 2048 + wave * 512));
    }
    __syncthreads();

    f32x4 acc[10] = {};
#pragma unroll
    for (int k4 = 0; k4 < 4; ++k4) {
        int ch = ((k4 << 2) + grp) ^ lm;
        bf16x8 a = *(const bf16x8*)(As + (wave * 16 + lm) * 128 + ch * 8);
#pragma unroll
        for (int n = 0; n < 10; ++n) {
            bf16x8 b = *(const bf16x8*)(Bs + (n * 16 + lm) * 128 + ch * 8);
            acc[n] = __builtin_amdgcn_mfma_f32_16x16x32_bf16(a, b, acc[n], 0, 0, 0);
        }
    }

#pragma unroll
    for (int n = 0; n < 10; ++n) {
#pragma unroll
        for (int r = 0; r < 4; ++r) {
            int row = mt * 64 + wave * 16 + grp * 4 + r;
            int col = n * 16 + lm;
            if (n < 8) atomicAdd(&kf32[(size_t)row * 128 + col], acc[n][r]);
            else       atomicAdd(&wbuf[(size_t)row * 32 + (col - 128)], acc[n][r]);
        }
    }
}

// ---------------------------------------------------------------------------
// bf16 MFMA GEMM, B^T layout (q projection)
// ---------------------------------------------------------------------------
__global__ __launch_bounds__(256, 2) void gemm_bf16_bt(
    const __hip_bfloat16* __restrict__ A, const __hip_bfloat16* __restrict__ BT,
    __hip_bfloat16* __restrict__ C, int M, int N, int K)
{
    __shared__ short As[128 * 32];
    __shared__ short Bs[128 * 32];
    const int tid = threadIdx.x;
    const int wave = tid >> 6, lane = tid & 63, grp = lane >> 4, lm = lane & 15;
    const int row0 = blockIdx.y * 128, col0 = blockIdx.x * 128;
    const short* Ag = (const short*)A;
    const short* Bg = (const short*)BT;

    f32x4 acc[2][8] = {};

    for (int kc = 0; kc < K; kc += 32) {
        __syncthreads();
#pragma unroll
        for (int is = 0; is < 2; ++is) {
            int r = is * 64 + (tid >> 2);
            async_copy16(Ag + (size_t)(row0 + r) * K + kc + (tid & 3) * 8,
                         (void*)(As + is * 2048 + wave * 512));
            async_copy16(Bg + (size_t)(col0 + r) * K + kc + (tid & 3) * 8,
                         (void*)(Bs + is * 2048 + wave * 512));
        }
        __syncthreads();
        bf16x8 a0 = *(const bf16x8*)(As + (wave * 32 + lm) * 32 + grp * 8);
        bf16x8 a1 = *(const bf16x8*)(As + (wave * 32 + 16 + lm) * 32 + grp * 8);
#pragma unroll
        for (int c = 0; c < 8; ++c) {
            bf16x8 b = *(const bf16x8*)(Bs + (c * 16 + lm) * 32 + grp * 8);
            acc[0][c] = __builtin_amdgcn_mfma_f32_16x16x32_bf16(a0, b, acc[0][c], 0, 0, 0);
            acc[1][c] = __builtin_amdgcn_mfma_f32_16x16x32_bf16(a1, b, acc[1][c], 0, 0, 0);
        }
    }
#pragma unroll
    for (int t = 0; t < 2; ++t)
#pragma unroll
        for (int c = 0; c < 8; ++c)
#pragma unroll
            for (int r = 0; r < 4; ++r) {
                int rr = row0 + wave * 32 + t * 16 + grp * 4 + r;
                int cc = col0 + c * 16 + lm;
                C[(size_t)rr * N + cc] = __float2bfloat16(acc[t][c][r]);
            }
}

// ---------------------------------------------------------------------------
// RoPE cos/sin table
// ---------------------------------------------------------------------------
__global__ void sincos_table_kernel(const int* __restrict__ positions,
                                    float* __restrict__ cosT, float* __restrict__ sinT)
{
    int g = blockIdx.x * blockDim.x + threadIdx.x;
    if (g >= S * 32) return;
    int s = g >> 5;
    int p = g & 31;
    double inv = pow(10000.0, -((double)(2 * p)) / 64.0);
    double ang = (double)positions[s] * inv;
    cosT[g] = (float)cos(ang);
    sinT[g] = (float)sin(ang);
}

// ---------------------------------------------------------------------------
// Per-row postprocess: optional LN, RoPE, FWHT. Reads f32 or bf16, writes bf16.
// ---------------------------------------------------------------------------
__global__ __launch_bounds__(128) void post_kernel(
    const void* in, int in_bf16, __hip_bfloat16* outb,
    const float* __restrict__ cosT, const float* __restrict__ sinT,
    const float* __restrict__ gamma, const float* __restrict__ beta,
    int heads, int do_ln)
{
    const int row = blockIdx.x;
    const int t = threadIdx.x;
    const int srow = row / heads;
    __shared__ float sm[128];
    __shared__ float red[2];

    float v;
    if (in_bf16) v = __bfloat162float(((const __hip_bfloat16*)in)[(size_t)row * 128 + t]);
    else         v = ((const float*)in)[(size_t)row * 128 + t];

    if (do_ln) {
        float sv = v;
#pragma unroll
        for (int o = 32; o > 0; o >>= 1) sv += __shfl_down(sv, o);
        if ((t & 63) == 0) red[t >> 6] = sv;
        __syncthreads();
        float mu = (red[0] + red[1]) * (1.0f / 128.0f);
        __syncthreads();
        float d = v - mu;
        float sq = d * d;
#pragma unroll
        for (int o = 32; o > 0; o >>= 1) sq += __shfl_down(sq, o);
        if ((t & 63) == 0) red[t >> 6] = sq;
        __syncthreads();
        float var = (red[0] + red[1]) * (1.0f / 128.0f);
        v = d * rsqrtf(var + 1e-6f) * gamma[t] + beta[t];
        __syncthreads();
    }
    sm[t] = v;
    __syncthreads();

    if (t < 32) {
        float c = cosT[(size_t)srow * 32 + t];
        float sn = sinT[(size_t)srow * 32 + t];
        float xe = sm[2 * t];
        float xo = sm[2 * t + 1];
        sm[2 * t]     = xe * c - xo * sn;
        sm[2 * t + 1] = xe * sn + xo * c;
    }
    __syncthreads();

    for (int hstep = 1; hstep < 128; hstep <<= 1) {
        int i = 0; float a = 0.f, b = 0.f;
        bool act = (t < 64);
        if (act) {
            i = ((t & ~(hstep - 1)) << 1) | (t & (hstep - 1));
            a = sm[i];
            b = sm[i + hstep];
        }
        __syncthreads();
        if (act) { sm[i] = a + b; sm[i + hstep] = a - b; }
        __syncthreads();
    }
    outb[(size_t)row * 128 + t] = __float2bfloat16(sm[t] * 0.08838834764831845f);
}

// ---------------------------------------------------------------------------
// MFMA logits: logits[i,j] = sum_h w[i,h]*relu(q[i,h,:].k[j,:]), causal mask.
// ---------------------------------------------------------------------------
__global__ __launch_bounds__(256, 2) void logits_mfma(
    const short* __restrict__ qb,   // S x (H*D) bf16 bits
    const short* __restrict__ kb,   // S x D bf16 bits
    const float* __restrict__ w,    // S x H
    float* __restrict__ out)
{
    const int bx = blockIdx.x, by = blockIdx.y;
    const int row0 = by * 128, col0 = bx * 128;
    const int tid = threadIdx.x;

    if (bx > by) {
        const float4 n4 = make_float4(NEGF, NEGF, NEGF, NEGF);
        int c = (tid & 31) * 4;
        for (int r = tid >> 5; r < 128; r += 8)
            *(float4*)&out[(size_t)(row0 + r) * S + col0 + c] = n4;
        return;
    }

    __shared__ short As[128 * 128];
    __shared__ short Bs[128 * 128];
    const int wave = tid >> 6, lane = tid & 63, grp = lane >> 4, lm = lane & 15;
    const int rhi = tid >> 4;
    const int e = (tid & 15) ^ rhi;

#pragma unroll
    for (int it = 0; it < 8; ++it) {
        int r = it * 16 + rhi;
        async_copy16(kb + (size_t)(col0 + r) * D + e * 8,
                     (void*)(Bs + it * 2048 + wave * 512));
    }

    f32x4 accP[2][8] = {};

    for (int h = 0; h < H; ++h) {
        __syncthreads();
#pragma unroll
        for (int it = 0; it < 8; ++it) {
            int r = it * 16 + rhi;
            async_copy16(qb + (size_t)(row0 + r) * (H * D) + h * D + e * 8,
                         (void*)(As + it * 2048 + wave * 512));
        }
        float wv[2][4];
#pragma unroll
        for (int t = 0; t < 2; ++t)
#pragma unroll
            for (int r = 0; r < 4; ++r)
                wv[t][r] = w[(size_t)(row0 + wave * 32 + t * 16 + grp * 4 + r) * H + h];
        __syncthreads();

        f32x4 accH[2][8] = {};
#pragma unroll
        for (int kc = 0; kc < 4; ++kc) {
            int ch = ((kc << 2) + grp) ^ lm;
            bf16x8 a0 = *(const bf16x8*)(As + (wave * 32 + lm) * 128 + ch * 8);
            bf16x8 a1 = *(const bf16x8*)(As + (wave * 32 + 16 + lm) * 128 + ch * 8);
#pragma unroll
            for (int c = 0; c < 8; ++c) {
                bf16x8 b = *(const bf16x8*)(Bs + (c * 16 + lm) * 128 + ch * 8);
                accH[0][c] = __builtin_amdgcn_mfma_f32_16x16x32_bf16(a0, b, accH[0][c], 0, 0, 0);
                accH[1][c] = __builtin_amdgcn_mfma_f32_16x16x32_bf16(a1, b, accH[1][c], 0, 0, 0);
            }
        }
#pragma unroll
        for (int t = 0; t < 2; ++t)
#pragma unroll
            for (int c = 0; c < 8; ++c)
#pragma unroll
                for (int r = 0; r < 4; ++r)
                    accP[t][c][r] += wv[t][r] * fmaxf(accH[t][c][r], 0.0f);
    }

#pragma unroll
    for (int t = 0; t < 2; ++t)
#pragma unroll
        for (int c = 0; c < 8; ++c)
#pragma unroll
            for (int r = 0; r < 4; ++r) {
                int rr = row0 + wave * 32 + t * 16 + grp * 4 + r;
                int cc = col0 + c * 16 + lm;
                out[(size_t)rr * S + cc] = (cc <= rr) ? accP[t][c][r] : NEGF;
            }
}

// ---------------------------------------------------------------------------
// Top-k via 4-round radix select (11-bit digits over unique 44-bit keys).
// ---------------------------------------------------------------------------
__device__ __forceinline__ unsigned mono32(float f)
{
    unsigned u = __float_as_uint(f);
    return (u & 0x80000000u) ? ~u : (u | 0x80000000u);
}

__global__ __launch_bounds__(256) void topk_select(
    const float* __restrict__ logits, float* __restrict__ out_idx)
{
    const int row = blockIdx.x;
    const int tid = threadIdx.x;
    const int valid = row + 1;
    float* orow = out_idx + (size_t)row * TOPK_N;

    if (valid <= TOPK_N) {
        for (int p = tid; p < TOPK_N; p += 256)
            orow[p] = (p < valid) ? (float)p : -1.0f;
        return;
    }

    __shared__ float vals[S];
    __shared__ unsigned hist[2048];
    __shared__ unsigned chunk[256];
    __shared__ unsigned long long sh_prefix;
    __shared__ int sh_rem;
    __shared__ unsigned sh_cnt;

    const float* lr = logits + (size_t)row * S;
    for (int j = tid; j < valid; j += 256) vals[j] = lr[j];
    if (tid == 0) { sh_prefix = 0ull; sh_rem = TOPK_N; sh_cnt = 0u; }
    __syncthreads();

    for (int rnd = 0; rnd < 4; ++rnd) {
        const int shift = 33 - 11 * rnd;
        for (int i = tid; i < 2048; i += 256) hist[i] = 0u;
        __syncthreads();
        const unsigned long long pref = sh_prefix;
        const int rem = sh_rem;
        const int hs = shift + 11;
        for (int j = tid; j < valid; j += 256) {
            unsigned long long key = (((unsigned long long)mono32(vals[j])) << 12)
                                   | (unsigned)(4095 - j);
            if ((key >> hs) == (pref >> hs))
                atomicAdd(&hist[(unsigned)(key >> shift) & 2047u], 1u);
        }
        __syncthreads();
        unsigned csum = 0;
#pragma unroll
        for (int d = 0; d < 8; ++d) csum += hist[tid * 8 + d];
        chunk[tid] = csum;
        __syncthreads();
        for (int off = 1; off < 256; off <<= 1) {
            unsigned v = (tid + off < 256) ? chunk[tid + off] : 0u;
            __syncthreads();
            chunk[tid] += v;
            __syncthreads();
        }
        unsigned A = (tid < 255) ? chunk[tid + 1] : 0u;
        for (int dd = 7; dd >= 0; --dd) {
            unsigned c = hist[tid * 8 + dd];
            if (c && A < (unsigned)rem && (unsigned)rem <= A + c) {
                sh_prefix = pref | ((unsigned long long)(tid * 8 + dd) << shift);
                sh_rem = rem - (int)A;
            }
            A += c;
        }
        __syncthreads();
    }

    const unsigned long long Kstar = sh_prefix;
    for (int j = tid; j < valid; j += 256) {
        unsigned long long key = (((unsigned long long)mono32(vals[j])) << 12)
                               | (unsigned)(4095 - j);
        if (key >= Kstar) {
            unsigned p = atomicAdd(&sh_cnt, 1u);
            orow[p] = (float)j;
        }
    }
}

// ---------------------------------------------------------------------------
extern "C" void kernel_launch(void* const* d_in, const int* in_sizes, int n_in,
                              void* d_out, int out_size, void* d_ws, size_t ws_size,
                              hipStream_t stream)
{
    const float* hidden    = (const float*)d_in[0];
    const float* q_lora    = (const float*)d_in[1];
    const int*   positions = (const int*)d_in[2];
    const float* Wq        = (const float*)d_in[3];
    const float* Wk        = (const float*)d_in[4];
    const float* k_gamma   = (const float*)d_in[5];
    const float* k_beta    = (const float*)d_in[6];
    const float* Wp        = (const float*)d_in[7];

    char* ws = (char*)d_ws;
    size_t off = 0;
    __hip_bfloat16* qb16 = (__hip_bfloat16*)(ws + off); off += (size_t)S * H * D * 2;     // 32 MB
    __hip_bfloat16* qlb  = (__hip_bfloat16*)(ws + off); off += (size_t)S * QLR * 2;       // 12.6 MB
    __hip_bfloat16* WqT  = (__hip_bfloat16*)(ws + off); off += (size_t)(H * D) * QLR * 2; // 12.6 MB
    __hip_bfloat16* hb   = (__hip_bfloat16*)(ws + off); off += (size_t)S * HID * 2;       // 16 MB
    __hip_bfloat16* WkpT = (__hip_bfloat16*)(ws + off); off += (size_t)KW_N * HID * 2;    // 0.64 MB
    float* kf32 = (float*)(ws + off); off += (size_t)S * D * 4;                            // 2 MB
    __hip_bfloat16* kb16 = (__hip_bfloat16*)(ws + off); off += (size_t)S * D * 2;          // 1 MB
    float* wbuf = (float*)(ws + off); off += (size_t)S * H * 4;
    float* cosT = (float*)(ws + off); off += (size_t)S * 32 * 4;
    float* sinT = (float*)(ws + off); off += (size_t)S * 32 * 4;

    float* out_logits = (float*)d_out;
    float* out_idx = out_logits + (size_t)S * S;

    // 1) casts for the q GEMM
    cast_bf16_kernel<<<(S * QLR / 4 + 255) / 256, 256, 0, stream>>>(q_lora, qlb, S * QLR / 4);
    transpose_cast_kernel<<<dim3((H * D) / 32, QLR / 32), 256, 0, stream>>>(Wq, WqT);

    // 2) q = q_lora @ Wq  (bf16 MFMA, bf16 out)
    gemm_bf16_bt<<<dim3((H * D) / 128, S / 128), 256, 0, stream>>>(
        qlb, WqT, qb16, S, H * D, QLR);

    // 3) fused k/w projection via split-K MFMA + f32 atomics
    cast_bf16_kernel<<<(S * HID / 4 + 255) / 256, 256, 0, stream>>>(hidden, hb, S * HID / 4);
    build_wkpT<<<(KW_N * HID + 255) / 256, 256, 0, stream>>>(Wk, Wp, WkpT);
    zero_f32<<<(S * D + 255) / 256, 256, 0, stream>>>(kf32, S * D);
    zero_f32<<<(S * H + 255) / 256, 256, 0, stream>>>(wbuf, S * H);
    kw_mfma<<<dim3(S / 64, HID / 128), 256, 0, stream>>>(
        (const short*)hb, (const short*)WkpT, kf32, wbuf);

    // 4) RoPE trig table
    sincos_table_kernel<<<(S * 32) / 256, 256, 0, stream>>>(positions, cosT, sinT);

    // 5) k: LN + RoPE + FWHT -> bf16 ; q: RoPE + FWHT in place (bf16)
    post_kernel<<<S, 128, 0, stream>>>(kf32, 0, kb16, cosT, sinT, k_gamma, k_beta, 1, 1);
    post_kernel<<<S * H, 128, 0, stream>>>(qb16, 1, qb16, cosT, sinT, nullptr, nullptr, H, 0);

    // 6) logits (bf16 MFMA) with causal mask
    logits_mfma<<<dim3(S / 128, S / 128), 256, 0, stream>>>(
        (const short*)qb16, (const short*)kb16, wbuf, out_logits);

    // 7) top-k indices (radix select, written as float)
    topk_select<<<S, 256, 0, stream>>>(out_logits, out_idx);
}

// Round 5
// 486.663 us; speedup vs baseline: 6.7370x; 1.0420x over previous
//
#include <hip/hip_runtime.h>
#include <hip/hip_bf16.h>
#include <math.h>

#define S 4096
#define H 32
#define D 128
#define QLR 1536
#define HID 2048
#define TOPK_N 2048
#define NEGF (-1e30f)
#define KW_N 160

typedef __attribute__((ext_vector_type(8))) short bf16x8;
typedef __attribute__((ext_vector_type(4))) float f32x4;

__device__ __forceinline__ void async_copy16(const void* g, void* l) {
    __builtin_amdgcn_global_load_lds(
        (const __attribute__((address_space(1))) unsigned int*)g,
        (__attribute__((address_space(3))) unsigned int*)l,
        16, 0, 0);
}

__device__ __forceinline__ unsigned short bf16bits(float f) {
    __hip_bfloat16 h = __float2bfloat16(f);
    return *(unsigned short*)&h;
}

__device__ __forceinline__ float bits2f(unsigned short u) {
    unsigned v = ((unsigned)u) << 16;
    return __uint_as_float(v);
}

// ---------------------------------------------------------------------------
// Cast f32 -> bf16 (elementwise, float4 granular)
// ---------------------------------------------------------------------------
__global__ __launch_bounds__(256) void cast_bf16_kernel(
    const float* __restrict__ in, __hip_bfloat16* __restrict__ out, int n4)
{
    int i = blockIdx.x * blockDim.x + threadIdx.x;
    if (i < n4) {
        float4 v = ((const float4*)in)[i];
        ushort4 pack;
        pack.x = bf16bits(v.x);
        pack.y = bf16bits(v.y);
        pack.z = bf16bits(v.z);
        pack.w = bf16bits(v.w);
        *(ushort4*)(out + (size_t)i * 4) = pack;
    }
}

__global__ __launch_bounds__(256) void zero_f32(float* __restrict__ p, int n)
{
    int i = blockIdx.x * blockDim.x + threadIdx.x;
    if (i < n) p[i] = 0.0f;
}

// ---------------------------------------------------------------------------
// Transpose + cast: Wq (1536 x 4096 f32) -> WqT (4096 x 1536 bf16)
// ---------------------------------------------------------------------------
__global__ __launch_bounds__(256) void transpose_cast_kernel(
    const float* __restrict__ in, __hip_bfloat16* __restrict__ out)
{
    __shared__ float sm[32][33];
    const int nb = blockIdx.x;
    const int kb = blockIdx.y;
    const int t = threadIdx.x;
    const int j = t & 31, i0 = t >> 5;
#pragma unroll
    for (int u = 0; u < 4; ++u) {
        int i = i0 + u * 8;
        sm[i][j] = in[(size_t)(kb * 32 + i) * 4096 + nb * 32 + j];
    }
    __syncthreads();
#pragma unroll
    for (int u = 0; u < 4; ++u) {
        int i = i0 + u * 8;
        out[(size_t)(nb * 32 + i) * 1536 + kb * 32 + j] = __float2bfloat16(sm[j][i]);
    }
}

// ---------------------------------------------------------------------------
// Build WkpT (160 x 2048 bf16): rows 0..127 = Wk^T, rows 128..159 = (Wp/64)^T
// ---------------------------------------------------------------------------
__global__ __launch_bounds__(256) void build_wkpT(
    const float* __restrict__ Wk, const float* __restrict__ Wp,
    __hip_bfloat16* __restrict__ WkpT)
{
    int g = blockIdx.x * blockDim.x + threadIdx.x;
    if (g >= KW_N * HID) return;
    int n = g / HID, k = g % HID;
    float v = (n < 128) ? Wk[(size_t)k * 128 + n]
                        : Wp[(size_t)k * 32 + (n - 128)] * 0.015625f;
    WkpT[g] = __float2bfloat16(v);
}

// ---------------------------------------------------------------------------
// Fused k/w projection, split-K MFMA (atomicAdd f32 partials)
// ---------------------------------------------------------------------------
__global__ __launch_bounds__(256, 2) void kw_mfma(
    const short* __restrict__ hb,
    const short* __restrict__ WkpT,
    float* __restrict__ kf32,
    float* __restrict__ wbuf)
{
    const int mt = blockIdx.x;
    const int kc = blockIdx.y;
    const int tid = threadIdx.x;
    const int wave = tid >> 6, lane = tid & 63, grp = lane >> 4, lm = lane & 15;
    __shared__ short As[64 * 128];
    __shared__ short Bs[KW_N * 128];

    const int rhi = tid >> 4;
    const int e = (tid & 15) ^ rhi;

#pragma unroll
    for (int it = 0; it < 4; ++it) {
        int r = it * 16 + rhi;
        async_copy16(hb + (size_t)(mt * 64 + r) * HID + kc * 128 + e * 8,
                     (void*)(As + it * 2048 + wave * 512));
    }
#pragma unroll
    for (int it = 0; it < 10; ++it) {
        int r = it * 16 + rhi;
        async_copy16(WkpT + (size_t)r * HID + kc * 128 + e * 8,
                     (void*)(Bs + it * 2048 + wave * 512));
    }
    __syncthreads();

    f32x4 acc[10] = {};
#pragma unroll
    for (int k4 = 0; k4 < 4; ++k4) {
        int ch = ((k4 << 2) + grp) ^ lm;
        bf16x8 a = *(const bf16x8*)(As + (wave * 16 + lm) * 128 + ch * 8);
#pragma unroll
        for (int n = 0; n < 10; ++n) {
            bf16x8 b = *(const bf16x8*)(Bs + (n * 16 + lm) * 128 + ch * 8);
            acc[n] = __builtin_amdgcn_mfma_f32_16x16x32_bf16(a, b, acc[n], 0, 0, 0);
        }
    }

#pragma unroll
    for (int n = 0; n < 10; ++n) {
#pragma unroll
        for (int r = 0; r < 4; ++r) {
            int row = mt * 64 + wave * 16 + grp * 4 + r;
            int col = n * 16 + lm;
            if (n < 8) atomicAdd(&kf32[(size_t)row * 128 + col], acc[n][r]);
            else       atomicAdd(&wbuf[(size_t)row * 32 + (col - 128)], acc[n][r]);
        }
    }
}

// ---------------------------------------------------------------------------
// bf16 MFMA GEMM, B^T layout (q projection)
// ---------------------------------------------------------------------------
__global__ __launch_bounds__(256, 2) void gemm_bf16_bt(
    const __hip_bfloat16* __restrict__ A, const __hip_bfloat16* __restrict__ BT,
    __hip_bfloat16* __restrict__ C, int M, int N, int K)
{
    __shared__ short As[128 * 32];
    __shared__ short Bs[128 * 32];
    const int tid = threadIdx.x;
    const int wave = tid >> 6, lane = tid & 63, grp = lane >> 4, lm = lane & 15;
    const int row0 = blockIdx.y * 128, col0 = blockIdx.x * 128;
    const short* Ag = (const short*)A;
    const short* Bg = (const short*)BT;

    f32x4 acc[2][8] = {};

    for (int kc = 0; kc < K; kc += 32) {
        __syncthreads();
#pragma unroll
        for (int is = 0; is < 2; ++is) {
            int r = is * 64 + (tid >> 2);
            async_copy16(Ag + (size_t)(row0 + r) * K + kc + (tid & 3) * 8,
                         (void*)(As + is * 2048 + wave * 512));
            async_copy16(Bg + (size_t)(col0 + r) * K + kc + (tid & 3) * 8,
                         (void*)(Bs + is * 2048 + wave * 512));
        }
        __syncthreads();
        bf16x8 a0 = *(const bf16x8*)(As + (wave * 32 + lm) * 32 + grp * 8);
        bf16x8 a1 = *(const bf16x8*)(As + (wave * 32 + 16 + lm) * 32 + grp * 8);
#pragma unroll
        for (int c = 0; c < 8; ++c) {
            bf16x8 b = *(const bf16x8*)(Bs + (c * 16 + lm) * 32 + grp * 8);
            acc[0][c] = __builtin_amdgcn_mfma_f32_16x16x32_bf16(a0, b, acc[0][c], 0, 0, 0);
            acc[1][c] = __builtin_amdgcn_mfma_f32_16x16x32_bf16(a1, b, acc[1][c], 0, 0, 0);
        }
    }
#pragma unroll
    for (int t = 0; t < 2; ++t)
#pragma unroll
        for (int c = 0; c < 8; ++c)
#pragma unroll
            for (int r = 0; r < 4; ++r) {
                int rr = row0 + wave * 32 + t * 16 + grp * 4 + r;
                int cc = col0 + c * 16 + lm;
                C[(size_t)rr * N + cc] = __float2bfloat16(acc[t][c][r]);
            }
}

// ---------------------------------------------------------------------------
// RoPE cos/sin table
// ---------------------------------------------------------------------------
__global__ void sincos_table_kernel(const int* __restrict__ positions,
                                    float* __restrict__ cosT, float* __restrict__ sinT)
{
    int g = blockIdx.x * blockDim.x + threadIdx.x;
    if (g >= S * 32) return;
    int s = g >> 5;
    int p = g & 31;
    double inv = pow(10000.0, -((double)(2 * p)) / 64.0);
    double ang = (double)positions[s] * inv;
    cosT[g] = (float)cos(ang);
    sinT[g] = (float)sin(ang);
}

// ---------------------------------------------------------------------------
// Wave-per-row postprocess: optional LN, RoPE, FWHT. No barriers, no LDS.
// Each lane holds elements (2l, 2l+1) of a 128-wide row.
// FWHT: stage h=1 in-lane; stages h=2..64 via shfl_xor(h/2).
// ---------------------------------------------------------------------------
__global__ __launch_bounds__(256) void post_wave(
    const void* __restrict__ in, int in_bf16, __hip_bfloat16* __restrict__ outb,
    const float* __restrict__ cosT, const float* __restrict__ sinT,
    const float* __restrict__ gamma, const float* __restrict__ beta,
    int heads, int do_ln, int nrows)
{
    const int row = blockIdx.x * 4 + (threadIdx.x >> 6);
    if (row >= nrows) return;
    const int l = threadIdx.x & 63;
    const int srow = row / heads;

    float a, b;
    if (in_bf16) {
        unsigned pr = ((const unsigned*)in)[(size_t)row * 64 + l];
        a = bits2f((unsigned short)(pr & 0xffff));
        b = bits2f((unsigned short)(pr >> 16));
    } else {
        float2 v = ((const float2*)in)[(size_t)row * 64 + l];
        a = v.x; b = v.y;
    }

    if (do_ln) {
        float s = a + b;
#pragma unroll
        for (int o = 1; o < 64; o <<= 1) s += __shfl_xor(s, o);
        float mu = s * (1.0f / 128.0f);
        float da = a - mu, db = b - mu;
        float sq = da * da + db * db;
#pragma unroll
        for (int o = 1; o < 64; o <<= 1) sq += __shfl_xor(sq, o);
        float rs = rsqrtf(sq * (1.0f / 128.0f) + 1e-6f);
        float2 g = ((const float2*)gamma)[l];
        float2 bt = ((const float2*)beta)[l];
        a = da * rs * g.x + bt.x;
        b = db * rs * g.y + bt.y;
    }

    // RoPE on first 64 elements: lane l<32 holds pair index t=l
    if (l < 32) {
        float c = cosT[(size_t)srow * 32 + l];
        float sn = sinT[(size_t)srow * 32 + l];
        float xe = a, xo = b;
        a = xe * c - xo * sn;
        b = xe * sn + xo * c;
    }

    // FWHT stage h=1 (in-lane)
    {
        float na = a + b, nb = a - b;
        a = na; b = nb;
    }
    // stages h=2..64: partner lane l ^ (h/2)
#pragma unroll
    for (int m = 1; m < 64; m <<= 1) {
        float pa = __shfl_xor(a, m);
        float pb = __shfl_xor(b, m);
        if (l & m) { a = pa - a; b = pb - b; }
        else       { a = a + pa; b = b + pb; }
    }

    const float sc = 0.08838834764831845f;
    unsigned outp = (unsigned)bf16bits(a * sc) | ((unsigned)bf16bits(b * sc) << 16);
    ((unsigned*)outb)[(size_t)row * 64 + l] = outp;
}

// ---------------------------------------------------------------------------
// MFMA logits with register-resident B (k) fragments across the head loop.
// Block tile 64x128 (4 waves, wave tile 32x64). LDS: Bs 32KB (staged once) +
// As 16KB (per head) = 48KB -> 3 blocks/CU.
// ---------------------------------------------------------------------------
__global__ __launch_bounds__(256, 3) void logits_mfma(
    const short* __restrict__ qb,   // S x (H*D) bf16 bits
    const short* __restrict__ kb,   // S x D bf16 bits
    const float* __restrict__ w,    // S x H
    float* __restrict__ out)
{
    const int bx = blockIdx.x;      // 0..31 col tiles (128 wide)
    const int by = blockIdx.y;      // 0..63 row tiles (64 tall)
    const int row0 = by * 64, col0 = bx * 128;
    const int tid = threadIdx.x;

    if (2 * bx > by) {
        // fully above the diagonal
        const float4 n4 = make_float4(NEGF, NEGF, NEGF, NEGF);
        int c = (tid & 31) * 4;
        for (int r = tid >> 5; r < 64; r += 8)
            *(float4*)&out[(size_t)(row0 + r) * S + col0 + c] = n4;
        return;
    }

    __shared__ short As[64 * 128];   // 16 KB
    __shared__ short Bs[128 * 128];  // 32 KB
    const int wave = tid >> 6, lane = tid & 63, grp = lane >> 4, lm = lane & 15;
    const int wr = wave >> 1, wc = wave & 1;
    const int rhi = tid >> 4;
    const int e = (tid & 15) ^ rhi;

    // stage k tile once
#pragma unroll
    for (int it = 0; it < 8; ++it) {
        int r = it * 16 + rhi;
        async_copy16(kb + (size_t)(col0 + r) * D + e * 8,
                     (void*)(Bs + it * 2048 + wave * 512));
    }
    __syncthreads();

    // cache all B fragments in registers (same k tile for every head)
    bf16x8 bfrag[4][4];
#pragma unroll
    for (int c = 0; c < 4; ++c)
#pragma unroll
        for (int kc = 0; kc < 4; ++kc)
            bfrag[c][kc] = *(const bf16x8*)(
                Bs + (wc * 64 + c * 16 + lm) * 128 + (((kc << 2) + grp) ^ lm) * 8);

    f32x4 accP[2][4] = {};

    for (int h = 0; h < H; ++h) {
        __syncthreads();  // all waves done reading As of prev head
#pragma unroll
        for (int it = 0; it < 4; ++it) {
            int r = it * 16 + rhi;
            async_copy16(qb + (size_t)(row0 + r) * (H * D) + h * D + e * 8,
                         (void*)(As + it * 2048 + wave * 512));
        }
        float wv[2][4];
#pragma unroll
        for (int t = 0; t < 2; ++t)
#pragma unroll
            for (int r = 0; r < 4; ++r)
                wv[t][r] = w[(size_t)(row0 + wr * 32 + t * 16 + grp * 4 + r) * H + h];
        __syncthreads();  // As ready

        f32x4 accH[2][4] = {};
#pragma unroll
        for (int kc = 0; kc < 4; ++kc) {
            int ch = ((kc << 2) + grp) ^ lm;
            bf16x8 a0 = *(const bf16x8*)(As + (wr * 32 + lm) * 128 + ch * 8);
            bf16x8 a1 = *(const bf16x8*)(As + (wr * 32 + 16 + lm) * 128 + ch * 8);
#pragma unroll
            for (int c = 0; c < 4; ++c) {
                accH[0][c] = __builtin_amdgcn_mfma_f32_16x16x32_bf16(a0, bfrag[c][kc], accH[0][c], 0, 0, 0);
                accH[1][c] = __builtin_amdgcn_mfma_f32_16x16x32_bf16(a1, bfrag[c][kc], accH[1][c], 0, 0, 0);
            }
        }
#pragma unroll
        for (int t = 0; t < 2; ++t)
#pragma unroll
            for (int c = 0; c < 4; ++c)
#pragma unroll
                for (int r = 0; r < 4; ++r)
                    accP[t][c][r] += wv[t][r] * fmaxf(accH[t][c][r], 0.0f);
    }

#pragma unroll
    for (int t = 0; t < 2; ++t)
#pragma unroll
        for (int c = 0; c < 4; ++c)
#pragma unroll
            for (int r = 0; r < 4; ++r) {
                int rr = row0 + wr * 32 + t * 16 + grp * 4 + r;
                int cc = col0 + wc * 64 + c * 16 + lm;
                out[(size_t)rr * S + cc] = (cc <= rr) ? accP[t][c][r] : NEGF;
            }
}

// ---------------------------------------------------------------------------
// Top-k via 4-round radix select (11-bit digits over unique 44-bit keys).
// ---------------------------------------------------------------------------
__device__ __forceinline__ unsigned mono32(float f)
{
    unsigned u = __float_as_uint(f);
    return (u & 0x80000000u) ? ~u : (u | 0x80000000u);
}

__global__ __launch_bounds__(256) void topk_select(
    const float* __restrict__ logits, float* __restrict__ out_idx)
{
    const int row = blockIdx.x;
    const int tid = threadIdx.x;
    const int valid = row + 1;
    float* orow = out_idx + (size_t)row * TOPK_N;

    if (valid <= TOPK_N) {
        for (int p = tid; p < TOPK_N; p += 256)
            orow[p] = (p < valid) ? (float)p : -1.0f;
        return;
    }

    __shared__ float vals[S];
    __shared__ unsigned hist[2048];
    __shared__ unsigned chunk[256];
    __shared__ unsigned long long sh_prefix;
    __shared__ int sh_rem;
    __shared__ unsigned sh_cnt;

    const float* lr = logits + (size_t)row * S;
    for (int j = tid; j < valid; j += 256) vals[j] = lr[j];
    if (tid == 0) { sh_prefix = 0ull; sh_rem = TOPK_N; sh_cnt = 0u; }
    __syncthreads();

    for (int rnd = 0; rnd < 4; ++rnd) {
        const int shift = 33 - 11 * rnd;
        for (int i = tid; i < 2048; i += 256) hist[i] = 0u;
        __syncthreads();
        const unsigned long long pref = sh_prefix;
        const int rem = sh_rem;
        const int hs = shift + 11;
        for (int j = tid; j < valid; j += 256) {
            unsigned long long key = (((unsigned long long)mono32(vals[j])) << 12)
                                   | (unsigned)(4095 - j);
            if ((key >> hs) == (pref >> hs))
                atomicAdd(&hist[(unsigned)(key >> shift) & 2047u], 1u);
        }
        __syncthreads();
        unsigned csum = 0;
#pragma unroll
        for (int d = 0; d < 8; ++d) csum += hist[tid * 8 + d];
        chunk[tid] = csum;
        __syncthreads();
        for (int off = 1; off < 256; off <<= 1) {
            unsigned v = (tid + off < 256) ? chunk[tid + off] : 0u;
            __syncthreads();
            chunk[tid] += v;
            __syncthreads();
        }
        unsigned A = (tid < 255) ? chunk[tid + 1] : 0u;
        for (int dd = 7; dd >= 0; --dd) {
            unsigned c = hist[tid * 8 + dd];
            if (c && A < (unsigned)rem && (unsigned)rem <= A + c) {
                sh_prefix = pref | ((unsigned long long)(tid * 8 + dd) << shift);
                sh_rem = rem - (int)A;
            }
            A += c;
        }
        __syncthreads();
    }

    const unsigned long long Kstar = sh_prefix;
    for (int j = tid; j < valid; j += 256) {
        unsigned long long key = (((unsigned long long)mono32(vals[j])) << 12)
                               | (unsigned)(4095 - j);
        if (key >= Kstar) {
            unsigned p = atomicAdd(&sh_cnt, 1u);
            orow[p] = (float)j;
        }
    }
}

// ---------------------------------------------------------------------------
extern "C" void kernel_launch(void* const* d_in, const int* in_sizes, int n_in,
                              void* d_out, int out_size, void* d_ws, size_t ws_size,
                              hipStream_t stream)
{
    const float* hidden    = (const float*)d_in[0];
    const float* q_lora    = (const float*)d_in[1];
    const int*   positions = (const int*)d_in[2];
    const float* Wq        = (const float*)d_in[3];
    const float* Wk        = (const float*)d_in[4];
    const float* k_gamma   = (const float*)d_in[5];
    const float* k_beta    = (const float*)d_in[6];
    const float* Wp        = (const float*)d_in[7];

    char* ws = (char*)d_ws;
    size_t off = 0;
    __hip_bfloat16* qb16 = (__hip_bfloat16*)(ws + off); off += (size_t)S * H * D * 2;
    __hip_bfloat16* qlb  = (__hip_bfloat16*)(ws + off); off += (size_t)S * QLR * 2;
    __hip_bfloat16* WqT  = (__hip_bfloat16*)(ws + off); off += (size_t)(H * D) * QLR * 2;
    __hip_bfloat16* hb   = (__hip_bfloat16*)(ws + off); off += (size_t)S * HID * 2;
    __hip_bfloat16* WkpT = (__hip_bfloat16*)(ws + off); off += (size_t)KW_N * HID * 2;
    float* kf32 = (float*)(ws + off); off += (size_t)S * D * 4;
    __hip_bfloat16* kb16 = (__hip_bfloat16*)(ws + off); off += (size_t)S * D * 2;
    float* wbuf = (float*)(ws + off); off += (size_t)S * H * 4;
    float* cosT = (float*)(ws + off); off += (size_t)S * 32 * 4;
    float* sinT = (float*)(ws + off); off += (size_t)S * 32 * 4;

    float* out_logits = (float*)d_out;
    float* out_idx = out_logits + (size_t)S * S;

    // 1) casts for the q GEMM
    cast_bf16_kernel<<<(S * QLR / 4 + 255) / 256, 256, 0, stream>>>(q_lora, qlb, S * QLR / 4);
    transpose_cast_kernel<<<dim3((H * D) / 32, QLR / 32), 256, 0, stream>>>(Wq, WqT);

    // 2) q = q_lora @ Wq  (bf16 MFMA, bf16 out)
    gemm_bf16_bt<<<dim3((H * D) / 128, S / 128), 256, 0, stream>>>(
        qlb, WqT, qb16, S, H * D, QLR);

    // 3) fused k/w projection via split-K MFMA + f32 atomics
    cast_bf16_kernel<<<(S * HID / 4 + 255) / 256, 256, 0, stream>>>(hidden, hb, S * HID / 4);
    build_wkpT<<<(KW_N * HID + 255) / 256, 256, 0, stream>>>(Wk, Wp, WkpT);
    zero_f32<<<(S * D + 255) / 256, 256, 0, stream>>>(kf32, S * D);
    zero_f32<<<(S * H + 255) / 256, 256, 0, stream>>>(wbuf, S * H);
    kw_mfma<<<dim3(S / 64, HID / 128), 256, 0, stream>>>(
        (const short*)hb, (const short*)WkpT, kf32, wbuf);

    // 4) RoPE trig table
    sincos_table_kernel<<<(S * 32) / 256, 256, 0, stream>>>(positions, cosT, sinT);

    // 5) k: LN + RoPE + FWHT -> bf16 ; q: RoPE + FWHT in place (bf16)
    post_wave<<<(S + 3) / 4, 256, 0, stream>>>(
        kf32, 0, kb16, cosT, sinT, k_gamma, k_beta, 1, 1, S);
    post_wave<<<(S * H + 3) / 4, 256, 0, stream>>>(
        qb16, 1, qb16, cosT, sinT, nullptr, nullptr, H, 0, S * H);

    // 6) logits (bf16 MFMA, reg-resident k fragments) with causal mask
    logits_mfma<<<dim3(S / 128, S / 64), 256, 0, stream>>>(
        (const short*)qb16, (const short*)kb16, wbuf, out_logits);

    // 7) top-k indices (radix select, written as float)
    topk_select<<<S, 256, 0, stream>>>(out_logits, out_idx);
}